// Round 10
// baseline (61.457 us; speedup 1.0000x reference)
//
#include <hip/hip_runtime.h>

#define NSTEP 50
#define STR 21        // LDS dwords per particle (max chunk 18 used + 3; odd -> bank-coprime)

__device__ __forceinline__ void lorenz(float x, float y, float z,
                                       float S, float R, float Bb,
                                       float c0, float c1, float c2,
                                       float& dx, float& dy, float& dz) {
    dx = S * (y - x) + c0;
    dy = x * (R - z) - y + c1;
    dz = x * y - Bb * z + c2;
}

// pack two f32 -> two bf16 (round-half-up) in one dword; lo in low half
__device__ __forceinline__ unsigned int bpack(float lo, float hi) {
    unsigned int a = (__builtin_bit_cast(unsigned int, lo) + 0x8000u) >> 16;
    unsigned int b = (__builtin_bit_cast(unsigned int, hi) + 0x8000u) & 0xFFFF0000u;
    return a | b;
}
__device__ __forceinline__ float bunpack_lo(unsigned int w) {
    return __builtin_bit_cast(float, w << 16);
}
__device__ __forceinline__ float bunpack_hi(unsigned int w) {
    return __builtin_bit_cast(float, w & 0xFFFF0000u);
}

__device__ __forceinline__ float tanh_fast(float x) {
    float e = __expf(2.0f * x);
    float r = __builtin_amdgcn_rcpf(e + 1.0f);
    return __builtin_fmaf(-2.0f, r, 1.0f);
}
__device__ __forceinline__ float sigmoid_fast(float x) {
    float e = __expf(-x);
    return __builtin_amdgcn_rcpf(1.0f + e);
}

// burst-flush one chunk: CNT packed dwords per particle, 64 particles.
// lane covers image dword i = 64k+lane; one float2 (2 f32) per dword, 8B-aligned.
template<int CNT>
__device__ __forceinline__ void flushT(const unsigned int* __restrict__ fb,
                                       float* __restrict__ outW,
                                       int lane, int e0dw) {
    #pragma unroll
    for (int k = 0; k < CNT; ++k) {
        const int i  = 64 * k + lane;
        const int pp = i / CNT;            // compile-time divisor -> magic mul
        const int j  = i - pp * CNT;
        const unsigned int v = fb[pp * STR + j];
        float2 o;
        o.x = bunpack_lo(v);
        o.y = bunpack_hi(v);
        *(float2*)(outW + pp * 150 + e0dw + 2 * j) = o;
    }
}

// 1 wave = 1 block = 64 particles. ~16 blocks/CU resident; per-SIMD slots are
// DIFFERENT blocks, so the hashed per-block chunk schedule staggers flush
// bursts within every SIMD: ~1/4 of waves flushing, ~3/4 pure-VALU at any time.
__global__ __launch_bounds__(64) void chaotic_embed_kernel(
    const float* __restrict__ features,
    const float* __restrict__ W1,  const float* __restrict__ b1,
    const float* __restrict__ W2,  const float* __restrict__ b2,
    const float* __restrict__ Wc1, const float* __restrict__ bc1,
    const float* __restrict__ Wc2, const float* __restrict__ bc2,
    const float* __restrict__ Wp1, const float* __restrict__ bp1,
    const float* __restrict__ Wp2, const float* __restrict__ bp2,
    float* __restrict__ out)
{
    __shared__ unsigned int buf[64 * STR];

    const int lane = threadIdx.x;
    const int bid  = blockIdx.x;
    const long p   = (long)bid * 64 + lane;

    const float4 f4 = ((const float4*)features)[p];
    const float fv[4] = {f4.x, f4.y, f4.z, f4.w};

    // ---- MLPs: compile-time weight indices -> uniform s_load, SGPR operands
    float h1[16];
    #pragma unroll
    for (int j = 0; j < 16; ++j) {
        float a = b1[j];
        #pragma unroll
        for (int i = 0; i < 4; ++i) a = __builtin_fmaf(fv[i], W1[i * 16 + j], a);
        h1[j] = tanh_fast(a);
    }
    float init[3];
    #pragma unroll
    for (int c = 0; c < 3; ++c) {
        float a = b2[c];
        #pragma unroll
        for (int j = 0; j < 16; ++j) a = __builtin_fmaf(h1[j], W2[j * 3 + c], a);
        init[c] = 2.0f * tanh_fast(a);
    }
    float hc[8];
    #pragma unroll
    for (int j = 0; j < 8; ++j) {
        float a = bc1[j];
        #pragma unroll
        for (int i = 0; i < 4; ++i) a = __builtin_fmaf(fv[i], Wc1[i * 8 + j], a);
        hc[j] = tanh_fast(a);
    }
    float coup[3];
    #pragma unroll
    for (int c = 0; c < 3; ++c) {
        float a = bc2[c];
        #pragma unroll
        for (int j = 0; j < 8; ++j) a = __builtin_fmaf(hc[j], Wc2[j * 3 + c], a);
        coup[c] = tanh_fast(a);
    }
    float hp[8];
    #pragma unroll
    for (int j = 0; j < 8; ++j) {
        float a = bp1[j];
        #pragma unroll
        for (int i = 0; i < 4; ++i) a = __builtin_fmaf(fv[i], Wp1[i * 8 + j], a);
        hp[j] = fmaxf(a, 0.0f);
    }
    float sc[3];
    #pragma unroll
    for (int c = 0; c < 3; ++c) {
        float a = bp2[c];
        #pragma unroll
        for (int j = 0; j < 8; ++j) a = __builtin_fmaf(hp[j], Wp2[j * 3 + c], a);
        sc[c] = sigmoid_fast(a);
    }
    const float S  = 10.0f * (0.5f + sc[0]);
    const float R  = 28.0f * (0.5f + sc[1]);
    const float Bb = (8.0f / 3.0f) * (0.5f + sc[2]);
    const float c0 = coup[0], c1 = coup[1], c2 = coup[2];
    const float H = 0.01f, HH = 0.5f * 0.01f, H6 = 0.01f / 6.0f;

    float sx = init[0], sy = init[1], sz = init[2];
    float px, py, pz;

    auto step = [&]() {
        float k1x, k1y, k1z, k2x, k2y, k2z, k3x, k3y, k3z, k4x, k4y, k4z;
        lorenz(sx, sy, sz, S, R, Bb, c0, c1, c2, k1x, k1y, k1z);
        lorenz(sx + HH * k1x, sy + HH * k1y, sz + HH * k1z,
               S, R, Bb, c0, c1, c2, k2x, k2y, k2z);
        lorenz(sx + HH * k2x, sy + HH * k2y, sz + HH * k2z,
               S, R, Bb, c0, c1, c2, k3x, k3y, k3z);
        lorenz(sx + H * k3x, sy + H * k3y, sz + H * k3z,
               S, R, Bb, c0, c1, c2, k4x, k4y, k4z);
        sx += H6 * (k1x + 2.0f * k2x + 2.0f * k3x + k4x);
        sy += H6 * (k1y + 2.0f * k2y + 2.0f * k3y + k4y);
        sz += H6 * (k1z + 2.0f * k2z + 2.0f * k3z + k4z);
    };

    unsigned int* row = buf + lane * STR;
    float* __restrict__ outW = out + (long)bid * (64 * 150);

    // hashed schedule variant: differs for co-resident blocks under
    // +1 / +4 / +256 dispatch strides (bit0 / bit2 / bit8 all mixed into low 2)
    const int variant = (bid ^ (bid >> 2) ^ (bid >> 8)) & 3;

    int e   = 0;                 // next trajectory entry to produce
    int len = 6 + 2 * variant;   // first chunk: 6/8/10/12 entries
    while (e < NSTEP) {
        if (len > NSTEP - e) len = NSTEP - e;
        const int len2 = len >> 1;
        // ---- pure-compute phase: len entries, packed to LDS (no global ops)
        int u = 0;
        for (int g = 0; g < len2; ++g) {
            if (e + 2 * g > 0) step();   // entry 0 is the init state
            px = sx; py = sy; pz = sz;
            step();
            row[u + 0] = bpack(px, py);
            row[u + 1] = bpack(pz, sx);
            row[u + 2] = bpack(sy, sz);
            u += 3;
        }
        // ---- burst-flush phase: this wave absorbs HBM backpressure while
        // differently-phased waves on the same SIMD keep computing.
        switch (len2) {
            case 6:  flushT<18>(buf, outW, lane, 3 * e); break;
            case 5:  flushT<15>(buf, outW, lane, 3 * e); break;
            case 4:  flushT<12>(buf, outW, lane, 3 * e); break;
            case 3:  flushT< 9>(buf, outW, lane, 3 * e); break;
            case 2:  flushT< 6>(buf, outW, lane, 3 * e); break;
            default: flushT< 3>(buf, outW, lane, 3 * e); break;
        }
        e += len;
        len = 12;
    }
}

extern "C" void kernel_launch(void* const* d_in, const int* in_sizes, int n_in,
                              void* d_out, int out_size, void* d_ws, size_t ws_size,
                              hipStream_t stream) {
    const float* features = (const float*)d_in[0];
    const float* W1  = (const float*)d_in[1];
    const float* b1  = (const float*)d_in[2];
    const float* W2  = (const float*)d_in[3];
    const float* b2  = (const float*)d_in[4];
    const float* Wc1 = (const float*)d_in[5];
    const float* bc1 = (const float*)d_in[6];
    const float* Wc2 = (const float*)d_in[7];
    const float* bc2 = (const float*)d_in[8];
    const float* Wp1 = (const float*)d_in[9];
    const float* bp1 = (const float*)d_in[10];
    const float* Wp2 = (const float*)d_in[11];
    const float* bp2 = (const float*)d_in[12];
    float* out = (float*)d_out;

    const int B = in_sizes[0] / 4;          // 262144
    const int grid = B / 64;                // 4096 one-wave blocks

    chaotic_embed_kernel<<<grid, 64, 0, stream>>>(
        features, W1, b1, W2, b2, Wc1, bc1, Wc2, bc2,
        Wp1, bp1, Wp2, bp2, out);
}

// Round 12
// 50.663 us; speedup vs baseline: 1.2131x; 1.2131x over previous
//
#include <hip/hip_runtime.h>

#define NT 512            // waves 0-3 compute, waves 4-7 store (1:1 pairs)
#define NSTEP 50
#define ROWW 75           // packed dwords per particle (150 bf16 = full row)
#define SLOT (64 * ROWW)  // 4800 dwords = 19.2 KB per pair

__device__ __forceinline__ void lorenz(float x, float y, float z,
                                       float S, float R, float Bb,
                                       float c0, float c1, float c2,
                                       float& dx, float& dy, float& dz) {
    dx = S * (y - x) + c0;
    dy = x * (R - z) - y + c1;
    dz = x * y - Bb * z + c2;
}

// pack two f32 -> two bf16 (round-half-up) in one dword; lo in low half
__device__ __forceinline__ unsigned int bpack(float lo, float hi) {
    unsigned int a = (__builtin_bit_cast(unsigned int, lo) + 0x8000u) >> 16;
    unsigned int b = (__builtin_bit_cast(unsigned int, hi) + 0x8000u) & 0xFFFF0000u;
    return a | b;
}
__device__ __forceinline__ float bunpack_lo(unsigned int w) {
    return __builtin_bit_cast(float, w << 16);
}
__device__ __forceinline__ float bunpack_hi(unsigned int w) {
    return __builtin_bit_cast(float, w & 0xFFFF0000u);
}

__device__ __forceinline__ float tanh_fast(float x) {
    float e = __expf(2.0f * x);
    float r = __builtin_amdgcn_rcpf(e + 1.0f);
    return __builtin_fmaf(-2.0f, r, 1.0f);
}
__device__ __forceinline__ float sigmoid_fast(float x) {
    float e = __expf(-x);
    return __builtin_amdgcn_rcpf(1.0f + e);
}

// bounded spin on an LDS flag; bounded so a sync bug fails visibly, not hangs
__device__ __forceinline__ void waitGE(const int* f, int v) {
    int guard = 0;
    while (*(const volatile int*)f < v) {
        __builtin_amdgcn_s_sleep(2);
        if (++guard > (1 << 20)) break;
    }
}

__global__ __launch_bounds__(NT) void chaotic_embed_kernel(
    const float* __restrict__ features,
    const float* __restrict__ W1,  const float* __restrict__ b1,
    const float* __restrict__ W2,  const float* __restrict__ b2,
    const float* __restrict__ Wc1, const float* __restrict__ bc1,
    const float* __restrict__ Wc2, const float* __restrict__ bc2,
    const float* __restrict__ Wp1, const float* __restrict__ bp1,
    const float* __restrict__ Wp2, const float* __restrict__ bp2,
    float* __restrict__ out)
{
    __shared__ unsigned int stage[4 * SLOT];   // one full-row slot per pair
    __shared__ int ready[4];                   // sets published by producer w
    __shared__ int freed[4];                   // sets register-captured by storer w

    const int tid  = threadIdx.x;
    const int wv   = tid >> 6;        // 0..3 compute, 4..7 storer
    const int lane = tid & 63;
    const int w    = wv & 3;          // pair index

    if (tid < 4) { ready[tid] = 0; freed[tid] = 0; }
    __syncthreads();

    const long blockBase = (long)blockIdx.x * 512;   // particles per block

    if (wv < 4) {
        // ================= COMPUTE WAVE (producer) =================
        unsigned int* row = stage + w * SLOT + lane * ROWW;  // stride 75: bank-coprime

        for (int s = 0; s < 2; ++s) {
            // slot reuse for set B: wait until storer captured set A into regs
            if (s == 1) waitGE(&freed[w], 1);

            const long p = blockBase + (long)w * 128 + (long)s * 64 + lane;
            const float4 f4 = ((const float4*)features)[p];
            const float fv[4] = {f4.x, f4.y, f4.z, f4.w};

            // ---- MLPs (uniform s_load weights, SGPR operands)
            float h1[16];
            #pragma unroll
            for (int j = 0; j < 16; ++j) {
                float a = b1[j];
                #pragma unroll
                for (int i = 0; i < 4; ++i) a = __builtin_fmaf(fv[i], W1[i * 16 + j], a);
                h1[j] = tanh_fast(a);
            }
            float init[3];
            #pragma unroll
            for (int c = 0; c < 3; ++c) {
                float a = b2[c];
                #pragma unroll
                for (int j = 0; j < 16; ++j) a = __builtin_fmaf(h1[j], W2[j * 3 + c], a);
                init[c] = 2.0f * tanh_fast(a);
            }
            float hc[8];
            #pragma unroll
            for (int j = 0; j < 8; ++j) {
                float a = bc1[j];
                #pragma unroll
                for (int i = 0; i < 4; ++i) a = __builtin_fmaf(fv[i], Wc1[i * 8 + j], a);
                hc[j] = tanh_fast(a);
            }
            float coup[3];
            #pragma unroll
            for (int c = 0; c < 3; ++c) {
                float a = bc2[c];
                #pragma unroll
                for (int j = 0; j < 8; ++j) a = __builtin_fmaf(hc[j], Wc2[j * 3 + c], a);
                coup[c] = tanh_fast(a);
            }
            float hp[8];
            #pragma unroll
            for (int j = 0; j < 8; ++j) {
                float a = bp1[j];
                #pragma unroll
                for (int i = 0; i < 4; ++i) a = __builtin_fmaf(fv[i], Wp1[i * 8 + j], a);
                hp[j] = fmaxf(a, 0.0f);
            }
            float sc[3];
            #pragma unroll
            for (int c = 0; c < 3; ++c) {
                float a = bp2[c];
                #pragma unroll
                for (int j = 0; j < 8; ++j) a = __builtin_fmaf(hp[j], Wp2[j * 3 + c], a);
                sc[c] = sigmoid_fast(a);
            }
            const float S  = 10.0f * (0.5f + sc[0]);
            const float R  = 28.0f * (0.5f + sc[1]);
            const float Bb = (8.0f / 3.0f) * (0.5f + sc[2]);
            const float c0 = coup[0], c1 = coup[1], c2 = coup[2];
            const float H = 0.01f, HH = 0.5f * 0.01f, H6 = 0.01f / 6.0f;

            float sx = init[0], sy = init[1], sz = init[2];
            float px = sx, py = sy, pz = sz;       // entry 0 = init

            int u = 0;
            #pragma unroll 2
            for (int t = 1; t < NSTEP; ++t) {
                float k1x, k1y, k1z, k2x, k2y, k2z, k3x, k3y, k3z, k4x, k4y, k4z;
                lorenz(sx, sy, sz, S, R, Bb, c0, c1, c2, k1x, k1y, k1z);
                lorenz(sx + HH * k1x, sy + HH * k1y, sz + HH * k1z,
                       S, R, Bb, c0, c1, c2, k2x, k2y, k2z);
                lorenz(sx + HH * k2x, sy + HH * k2y, sz + HH * k2z,
                       S, R, Bb, c0, c1, c2, k3x, k3y, k3z);
                lorenz(sx + H * k3x, sy + H * k3y, sz + H * k3z,
                       S, R, Bb, c0, c1, c2, k4x, k4y, k4z);
                sx += H6 * (k1x + 2.0f * k2x + 2.0f * k3x + k4x);
                sy += H6 * (k1y + 2.0f * k2y + 2.0f * k3y + k4y);
                sz += H6 * (k1z + 2.0f * k2z + 2.0f * k3z + k4z);

                if (t & 1) {                       // pack pair (t-1, t)
                    row[u + 0] = bpack(px, py);
                    row[u + 1] = bpack(pz, sx);
                    row[u + 2] = bpack(sy, sz);
                    u += 3;
                } else {
                    px = sx; py = sy; pz = sz;
                }
            }

            __threadfence_block();                 // ds_writes visible in order
            if (lane == 0) *(volatile int*)&ready[w] = s + 1;
        }
    } else {
        // ================= STORER WAVE (consumer) =================
        // Register-relay: capture the whole slot into VGPRs, free the slot
        // immediately, then stream contiguous dwordx4 stores and absorb all
        // HBM backpressure here (this wave has nothing else to do).
        const uint2* __restrict__ img2 = (const uint2*)(stage + w * SLOT);

        for (int s = 0; s < 2; ++s) {
            waitGE(&ready[w], s + 1);

            uint2 pr[38];
            #pragma unroll
            for (int k = 0; k < 38; ++k) {
                const int g = 64 * k + lane;       // 2400 uint2 total
                if (k < 37 || lane < 32) pr[k] = img2[g];
            }
            __threadfence_block();                 // reads retired before flag
            if (lane == 0) *(volatile int*)&freed[w] = s + 1;

            float4* __restrict__ outv = (float4*)(out +
                (blockBase + (long)w * 128 + (long)s * 64) * (3 * NSTEP));
            #pragma unroll
            for (int k = 0; k < 38; ++k) {
                const int g = 64 * k + lane;
                if (k < 37 || lane < 32) {
                    float4 v;
                    v.x = bunpack_lo(pr[k].x);
                    v.y = bunpack_hi(pr[k].x);
                    v.z = bunpack_lo(pr[k].y);
                    v.w = bunpack_hi(pr[k].y);
                    outv[g] = v;                   // 1 KB contiguous per instr
                }
            }
        }
    }
}

extern "C" void kernel_launch(void* const* d_in, const int* in_sizes, int n_in,
                              void* d_out, int out_size, void* d_ws, size_t ws_size,
                              hipStream_t stream) {
    const float* features = (const float*)d_in[0];
    const float* W1  = (const float*)d_in[1];
    const float* b1  = (const float*)d_in[2];
    const float* W2  = (const float*)d_in[3];
    const float* b2  = (const float*)d_in[4];
    const float* Wc1 = (const float*)d_in[5];
    const float* bc1 = (const float*)d_in[6];
    const float* Wc2 = (const float*)d_in[7];
    const float* bc2 = (const float*)d_in[8];
    const float* Wp1 = (const float*)d_in[9];
    const float* bp1 = (const float*)d_in[10];
    const float* Wp2 = (const float*)d_in[11];
    const float* bp2 = (const float*)d_in[12];
    float* out = (float*)d_out;

    const int B = in_sizes[0] / 4;          // 262144
    const int grid = B / 512;               // 512 blocks, 2/CU, all resident

    chaotic_embed_kernel<<<grid, NT, 0, stream>>>(
        features, W1, b1, W2, b2, Wc1, bc1, Wc2, bc2,
        Wp1, bp1, Wp2, bp2, out);
}